// Round 9
// baseline (262.908 us; speedup 1.0000x reference)
//
#include <hip/hip_runtime.h>

// Problem constants (fixed by the reference)
#define B_     32
#define C_IN_  512
#define H_     56
#define W_     56
#define HW_    (H_ * W_)        // 3136
#define C_ENC_ 64
#define K_     256
#define BHW_   (B_ * HW_)       // 100352
#define PTS_ROW_ (3 + C_ENC_)   // 67

typedef float f32x2 __attribute__((ext_vector_type(2)));

// ---------------------------------------------------------------------------
// k1: transpose conv_w [C_ENC, C_IN] -> Wt [C_IN, C_ENC] (o-contiguous rows)
// ---------------------------------------------------------------------------
__global__ __launch_bounds__(256) void k_transpose_w(
        const float* __restrict__ w, float* __restrict__ wt) {
    int i = blockIdx.x * 256 + threadIdx.x;          // 0 .. 32767
    if (i < C_ENC_ * C_IN_) {
        int o = i / C_IN_;
        int c = i % C_IN_;
        wt[c * C_ENC_ + o] = w[i];
    }
}

// ---------------------------------------------------------------------------
// k2 v9: pure 1x1 conv -> feats[b][pix][o].  GEMM-style lane map.
// R8 falsified {FMA-issue, VMEM-count, barrier-count} as the bottleneck;
// remaining defect shared by v4-v8: W streamed via s_load with SGPR file
// maxed (96-112) and 4 distinct 32KB W-slices thrashing the 16KB sK$ ->
// exposed lgkmcnt stalls between FMA bursts (VALUBusy 34% everywhere).
// v9 kills the scalar-W path:
//   lane l: po=l&15 -> outs po*4..+3 (W = per-lane float4 vector load,
//           256B/wave/channel, identical stream for ALL waves -> L1-hot)
//           pg=l>>4 -> pixels pg*4..+3 (x = broadcast float4 from L1/L2)
//   no LDS, no barriers, no inline asm; 2 loads + 8 pk-FMA per channel;
//   compiler pipelines via unroll-4 (vmcnt-tracked vector loads).
//   feats layout [b][pix][64o]: per-pixel float4 stores -> 256B-dense.
// NUMERICS: acc chain = bias then c-ascending fmaf per (pixel,o) ->
// bit-identical feats to all passing rounds (pk lanes are independent).
// ---------------------------------------------------------------------------
__global__ __launch_bounds__(256) void k_conv(
        const float* __restrict__ F, const float* __restrict__ wt,
        const float* __restrict__ bias, float* __restrict__ feats) {
    int t = threadIdx.x;
    int l = t & 63;
    int wv = t >> 6;                                 // wave: 16-pixel subset
    int po = l & 15;
    int pg = l >> 4;
    int pb = blockIdx.x;                             // 0..1567
    int b = pb / 49;                                 // 3136/64 = 49
    int pix0 = (pb % 49) * 64 + wv * 16 + pg * 4;    // lane's first pixel

    const float* fx = F + (size_t)b * C_IN_ * HW_ + pix0;   // + c*HW_
    const float* wp = wt + po * 4;                          // + c*64

    f32x2 acc2[4][2];
    float4 bi = *(const float4*)(bias + po * 4);
    #pragma unroll
    for (int j = 0; j < 4; ++j) {
        acc2[j][0][0] = bi.x; acc2[j][0][1] = bi.y;
        acc2[j][1][0] = bi.z; acc2[j][1][1] = bi.w;
    }

    #pragma unroll 4
    for (int c = 0; c < C_IN_; ++c) {
        float4 w4 = *(const float4*)(wp + (size_t)c * C_ENC_);
        float4 x4 = *(const float4*)(fx + (size_t)c * HW_);
        f32x2 wlo; wlo[0] = w4.x; wlo[1] = w4.y;
        f32x2 whi; whi[0] = w4.z; whi[1] = w4.w;
        float xs[4]; xs[0] = x4.x; xs[1] = x4.y; xs[2] = x4.z; xs[3] = x4.w;
        #pragma unroll
        for (int j = 0; j < 4; ++j) {
            f32x2 x2; x2[0] = xs[j]; x2[1] = xs[j];
            acc2[j][0] = __builtin_elementwise_fma(x2, wlo, acc2[j][0]);
            acc2[j][1] = __builtin_elementwise_fma(x2, whi, acc2[j][1]);
        }
    }

    // feats[b][pix][o]: one float4 per owned (pixel, 4-out group)
    float* fo = feats + ((size_t)b * HW_ + pix0) * C_ENC_ + po * 4;
    #pragma unroll
    for (int j = 0; j < 4; ++j) {
        float4 v;
        v.x = acc2[j][0][0]; v.y = acc2[j][0][1];
        v.z = acc2[j][1][0]; v.w = acc2[j][1][1];
        *(float4*)(fo + (size_t)j * C_ENC_) = v;
    }
}

// ---------------------------------------------------------------------------
// k2b: norms[p] = sum_o feats[p][o]^2, sequential o=0..63 fmaf chain —
// exactly the v2-v4 passing order, on bit-identical feats -> bit-identical
// norms -> identical top-k selection. Coalesced float4 row reads (L2-hot).
// ---------------------------------------------------------------------------
__global__ __launch_bounds__(256) void k_norm(
        const float* __restrict__ feats, float* __restrict__ norms) {
    int p = blockIdx.x * 256 + threadIdx.x;          // 392*256 == 100352
    const float* fr = feats + (size_t)p * C_ENC_;
    float nrm = 0.0f;
    #pragma unroll
    for (int q = 0; q < 16; ++q) {
        float4 v = *(const float4*)(fr + q * 4);
        nrm = fmaf(v.x, v.x, nrm);
        nrm = fmaf(v.y, v.y, nrm);
        nrm = fmaf(v.z, v.z, nrm);
        nrm = fmaf(v.w, v.w, nrm);
    }
    norms[p] = nrm;
}

// ---------------------------------------------------------------------------
// k3 (unchanged, passed R3-R8): radix-select exact 256th-largest key,
// compact >= T, bitonic-sort 512 -> exact jax.lax.top_k order.
// Also writes the full sw plane.
// ---------------------------------------------------------------------------
__global__ __launch_bounds__(512) void k_topk(
        const float* __restrict__ norms, unsigned int* __restrict__ topk,
        float* __restrict__ sw_out) {
    __shared__ unsigned int keys[HW_];               // 12.25 KB
    __shared__ unsigned int hist[256];
    __shared__ unsigned long long sortbuf[512];      // 4 KB
    __shared__ unsigned int s_prefix, s_need, s_cnt;
    __shared__ unsigned char flags[HW_];

    int b = blockIdx.x;
    int t = threadIdx.x;
    const float* nb = norms + b * HW_;

    for (int i = t; i < HW_; i += 512) {
        keys[i] = __float_as_uint(nb[i]);
        flags[i] = 0;
    }
    if (t == 0) { s_prefix = 0u; s_need = K_; s_cnt = 0u; }
    for (int i = t; i < 512; i += 512) sortbuf[i] = ~0ULL;

    for (int r = 0; r < 4; ++r) {
        if (t < 256) hist[t] = 0u;
        __syncthreads();
        unsigned int pfx = s_prefix;
        int shift = 24 - 8 * r;
        for (int i = t; i < HW_; i += 512) {
            unsigned int k = keys[i];
            bool ok = (r == 0) || ((k >> (32 - 8 * r)) == pfx);
            if (ok) atomicAdd(&hist[(k >> shift) & 0xFFu], 1u);
        }
        __syncthreads();
        if (t < 64) {                                // wave 0: suffix-scan
            unsigned int h0 = hist[4 * t + 0];
            unsigned int h1 = hist[4 * t + 1];
            unsigned int h2 = hist[4 * t + 2];
            unsigned int h3 = hist[4 * t + 3];
            unsigned int tot = h0 + h1 + h2 + h3;
            unsigned int suf = tot;
            #pragma unroll
            for (int off = 1; off < 64; off <<= 1) {
                unsigned int v = __shfl_down(suf, off);
                suf += (t + off < 64) ? v : 0u;
            }
            unsigned int g0 = suf;
            unsigned int g1 = suf - h0;
            unsigned int g2 = g1 - h1;
            unsigned int g3 = g2 - h2;
            unsigned int g4 = g3 - h3;
            unsigned int need = s_need;
            if (g0 >= need && g1 < need) { s_prefix = (pfx << 8) | (4u*t+0u); s_need = need - g1; }
            if (g1 >= need && g2 < need) { s_prefix = (pfx << 8) | (4u*t+1u); s_need = need - g2; }
            if (g2 >= need && g3 < need) { s_prefix = (pfx << 8) | (4u*t+2u); s_need = need - g3; }
            if (g3 >= need && g4 < need) { s_prefix = (pfx << 8) | (4u*t+3u); s_need = need - g4; }
        }
        __syncthreads();
    }
    unsigned int T = s_prefix;

    for (int i = t; i < HW_; i += 512) {
        unsigned int k = keys[i];
        if (k >= T) {
            unsigned int pos = atomicAdd(&s_cnt, 1u);
            if (pos < 512)
                sortbuf[pos] = ((unsigned long long)(~k) << 32) | (unsigned int)i;
        }
    }
    __syncthreads();

    for (int kk = 2; kk <= 512; kk <<= 1) {
        for (int j = kk >> 1; j > 0; j >>= 1) {
            int ixj = t ^ j;
            if (ixj > t) {
                unsigned long long a = sortbuf[t], c = sortbuf[ixj];
                bool up = ((t & kk) == 0);
                if ((a > c) == up) { sortbuf[t] = c; sortbuf[ixj] = a; }
            }
            __syncthreads();
        }
    }

    if (t < K_) {
        unsigned long long e = sortbuf[t];
        unsigned int idx = (unsigned int)(e & 0xFFFFFFFFu);
        topk[b * K_ + t] = idx;
        flags[idx] = 1;
    }
    __syncthreads();

    float* swb = sw_out + b * HW_;
    for (int i = t; i < HW_; i += 512)
        swb[i] = flags[i] ? 1.0f : 0.0f;
}

// ---------------------------------------------------------------------------
// k4 v3: gather with [b][pix][o] layout: lane o reads feats[b][p][o] ->
// one dense 256B read per wave. Writes the 67-float points row.
// ---------------------------------------------------------------------------
__global__ __launch_bounds__(64) void k_points(
        const float* __restrict__ feats, const unsigned int* __restrict__ topk,
        float* __restrict__ points) {
    int bk = blockIdx.x;                             // 0 .. B*K-1
    int b = bk >> 8;                                 // K = 256
    int o = threadIdx.x;
    unsigned int p = topk[bk];

    float v = feats[((size_t)b * HW_ + p) * C_ENC_ + o];
    float* row = points + (size_t)bk * PTS_ROW_;
    row[3 + o] = v;
    if (o == 0) {
        row[0] = (float)(p % W_);                    // abs_ (x)
        row[1] = (float)(p / W_);                    // ord_ (y)
        row[2] = 0.0f;                               // depth
    }
}

// ---------------------------------------------------------------------------
// k5 v3: x_out[b][o] = mean over K of feats[b][idx_k][o], k ascending
// (reference order). Dense 256B read per k. Indices staged in LDS.
// ---------------------------------------------------------------------------
__global__ __launch_bounds__(64) void k_xout(
        const float* __restrict__ feats, const unsigned int* __restrict__ topk,
        float* __restrict__ xout) {
    __shared__ unsigned int sidx[K_];
    int b = blockIdx.x;
    int t = threadIdx.x;
    for (int r = t; r < K_; r += 64) sidx[r] = topk[b * K_ + r];
    __syncthreads();

    const float* fb = feats + (size_t)b * HW_ * C_ENC_ + t;
    float s = 0.0f;
    #pragma unroll 8
    for (int k = 0; k < K_; ++k) s += fb[(size_t)sidx[k] * C_ENC_];
    xout[b * C_ENC_ + t] = s * (1.0f / K_);
}

// ---------------------------------------------------------------------------
extern "C" void kernel_launch(void* const* d_in, const int* in_sizes, int n_in,
                              void* d_out, int out_size, void* d_ws, size_t ws_size,
                              hipStream_t stream) {
    const float* F    = (const float*)d_in[0];       // [B, C_IN, H, W]
    const float* w    = (const float*)d_in[1];       // [C_ENC, C_IN]
    const float* bias = (const float*)d_in[2];       // [C_ENC]

    float* out    = (float*)d_out;
    float* xout   = out;                             // [B, C_ENC]      (2048)
    float* sw     = out + B_ * C_ENC_;               // [B, 1, H, W]    (100352)
    float* points = sw + BHW_;                       // [B, K, 67]      (548864)

    // workspace: feats [B,HW,64] 25.7MB | Wt 128KB | norms 392KB | topk 32KB
    float* feats         = (float*)d_ws;
    float* wt            = feats + (size_t)BHW_ * C_ENC_;
    float* norms         = wt + C_IN_ * C_ENC_;
    unsigned int* topk   = (unsigned int*)(norms + BHW_);

    k_transpose_w<<<128, 256, 0, stream>>>(w, wt);
    k_conv       <<<BHW_ / 64, 256, 0, stream>>>(F, wt, bias, feats);
    k_norm       <<<BHW_ / 256, 256, 0, stream>>>(feats, norms);
    k_topk       <<<B_, 512, 0, stream>>>(norms, topk, sw);
    k_points     <<<B_ * K_, 64, 0, stream>>>(feats, topk, points);
    k_xout       <<<B_, 64, 0, stream>>>(feats, topk, xout);
}

// Round 10
// 175.818 us; speedup vs baseline: 1.4953x; 1.4953x over previous
//
#include <hip/hip_runtime.h>

// Problem constants (fixed by the reference)
#define B_     32
#define C_IN_  512
#define H_     56
#define W_     56
#define HW_    (H_ * W_)        // 3136
#define C_ENC_ 64
#define K_     256
#define BHW_   (B_ * HW_)       // 100352
#define PTS_ROW_ (3 + C_ENC_)   // 67

#define CSTEP_ 64               // channels per pipeline step
#define NSTEP_ (C_IN_ / CSTEP_) // 8

typedef float f32x2 __attribute__((ext_vector_type(2)));

// ---------------------------------------------------------------------------
// k1: transpose conv_w [C_ENC, C_IN] -> Wt [C_IN, C_ENC] (o-contiguous rows)
// ---------------------------------------------------------------------------
__global__ __launch_bounds__(256) void k_transpose_w(
        const float* __restrict__ w, float* __restrict__ wt) {
    int i = blockIdx.x * 256 + threadIdx.x;          // 0 .. 32767
    if (i < C_ENC_ * C_IN_) {
        int o = i / C_IN_;
        int c = i % C_IN_;
        wt[c * C_ENC_ + o] = w[i];
    }
}

// async global->LDS, 16 B per lane: 64 lanes x 16B = 1 KB = 4 channel rows
// of 64 pixels. LDS dest = wave-uniform base + lane*16 (linear).
__device__ __forceinline__ void gload_lds16(const float* g, float* l) {
    __builtin_amdgcn_global_load_lds(
        (const __attribute__((address_space(1))) void*)g,
        (__attribute__((address_space(3))) void*)l, 16, 0, 0);
}

// ---------------------------------------------------------------------------
// k2 v10: 1x1 conv -> feats[b][pix][o].  v8 staging + v9 W-path.
// Diagnosis: all ~140us variants shared a 512-deep per-wave scalar-W stream
// (SGPR maxed at 112, ~3-4 s_loads in flight at ~200cy L2 latency -> the
// ~90us distributed stall; VALUBusy 34%). v9 moved W to VMEM but also moved
// x to per-lane global float4 -> VGPR=32, loop rolled, latency-bound (328us).
// v10: lane l -> po=l&15 (outs po*4..+3), pg=l>>4 (pixels pg*4..+3 of wave's
// 16-pixel subset wv):
//   - W: per-lane float4 VMEM (po-dependent addr); same 16KB/step for every
//     wave & block -> L1-hot. NO scalar loads in the loop.
//   - x: staged via gload_lds16 (v8 schedule: 2-phase, 1 barrier/step);
//     read as ONE ds_read_b128 (4 pixels, 16B-aligned; 4 distinct addrs on
//     disjoint bank quads -> conflict-free broadcast).
//   - per channel/thread: 1 VMEM + 1 ds_read + 8 pk-FMA; unroll 4.
// NUMERICS: per-(pixel,o) chain = bias then c-ascending fmaf -> feats
// bit-identical to all passing rounds.
// ---------------------------------------------------------------------------
__global__ __launch_bounds__(256) void k_conv(
        const float* __restrict__ F, const float* __restrict__ wt,
        const float* __restrict__ bias, float* __restrict__ feats) {
    __shared__ float xbuf[2][CSTEP_][64];            // 32 KB double buffer

    int t = threadIdx.x;
    int l = t & 63;
    int wv = t >> 6;                                 // wave's 16-pixel subset
    int po = l & 15;                                 // -> outs po*4..po*4+3
    int pg = l >> 4;                                 // -> pixels pg*4..pg*4+3
    int pb = blockIdx.x;                             // 0..1567
    int b = pb / 49;                                 // 3136/64 = 49
    int pixB = (pb % 49) * 64;                       // block's first pixel
    int pixT = wv * 16 + pg * 4;                     // thread's pixel offset

    // staging base: lane l covers channel +(l>>4), pixel (l&15)*4..+3
    const float* fs = F + (size_t)b * (C_IN_ * HW_)
                        + (size_t)(l >> 4) * HW_ + pixB + (l & 15) * 4;
    const float* wp = wt + po * 4;                   // + c*C_ENC_

    f32x2 acc2[4][2];
    float4 bi = *(const float4*)(bias + po * 4);
    #pragma unroll
    for (int j = 0; j < 4; ++j) {
        acc2[j][0][0] = bi.x; acc2[j][0][1] = bi.y;
        acc2[j][1][0] = bi.z; acc2[j][1][1] = bi.w;
    }

    // prologue: stage step 0 — wave wv stages channels wv*16..wv*16+15
    #pragma unroll
    for (int u = 0; u < 4; ++u)
        gload_lds16(fs + (size_t)(wv * 16 + u * 4) * HW_,
                    &xbuf[0][wv * 16 + u * 4][0]);
    asm volatile("s_waitcnt vmcnt(0)" ::: "memory");
    __syncthreads();

    for (int s = 0; s < NSTEP_; ++s) {
        // phase 1: issue stage(s+1) — in flight under compute(s)
        if (s + 1 < NSTEP_) {
            int cn = (s + 1) * CSTEP_ + wv * 16;
            float* dst = &xbuf[(s + 1) & 1][wv * 16][0];
            #pragma unroll
            for (int u = 0; u < 4; ++u)
                gload_lds16(fs + (size_t)(cn + u * 4) * HW_, dst + u * 4 * 64);
        }
        // phase 2: compute step s; W via per-lane float4 (L1-hot),
        // x via ds_read_b128 (4 pixels)
        {
            int cb = s * CSTEP_;
            #pragma unroll 4
            for (int cl = 0; cl < CSTEP_; ++cl) {
                float4 w4 = *(const float4*)(wp + (size_t)(cb + cl) * C_ENC_);
                float4 x4 = *(const float4*)(&xbuf[s & 1][cl][pixT]);
                f32x2 wlo; wlo[0] = w4.x; wlo[1] = w4.y;
                f32x2 whi; whi[0] = w4.z; whi[1] = w4.w;
                float xs[4]; xs[0] = x4.x; xs[1] = x4.y; xs[2] = x4.z; xs[3] = x4.w;
                #pragma unroll
                for (int j = 0; j < 4; ++j) {
                    f32x2 x2; x2[0] = xs[j]; x2[1] = xs[j];
                    acc2[j][0] = __builtin_elementwise_fma(x2, wlo, acc2[j][0]);
                    acc2[j][1] = __builtin_elementwise_fma(x2, whi, acc2[j][1]);
                }
            }
        }
        // phase 3: drain + barrier once per step
        asm volatile("s_waitcnt vmcnt(0)" ::: "memory");
        __syncthreads();
    }

    // feats[b][pix][o]: one float4 per owned (pixel, 4-out group)
    float* fo = feats + ((size_t)b * HW_ + pixB + pixT) * C_ENC_ + po * 4;
    #pragma unroll
    for (int j = 0; j < 4; ++j) {
        float4 v;
        v.x = acc2[j][0][0]; v.y = acc2[j][0][1];
        v.z = acc2[j][1][0]; v.w = acc2[j][1][1];
        *(float4*)(fo + (size_t)j * C_ENC_) = v;
    }
}

// ---------------------------------------------------------------------------
// k2b: norms[p] = sum_o feats[p][o]^2, sequential o=0..63 fmaf chain —
// exactly the original passing order on bit-identical feats -> bit-identical
// norms -> identical top-k selection. Coalesced float4 row reads.
// ---------------------------------------------------------------------------
__global__ __launch_bounds__(256) void k_norm(
        const float* __restrict__ feats, float* __restrict__ norms) {
    int p = blockIdx.x * 256 + threadIdx.x;          // 392*256 == 100352
    const float* fr = feats + (size_t)p * C_ENC_;
    float nrm = 0.0f;
    #pragma unroll
    for (int q = 0; q < 16; ++q) {
        float4 v = *(const float4*)(fr + q * 4);
        nrm = fmaf(v.x, v.x, nrm);
        nrm = fmaf(v.y, v.y, nrm);
        nrm = fmaf(v.z, v.z, nrm);
        nrm = fmaf(v.w, v.w, nrm);
    }
    norms[p] = nrm;
}

// ---------------------------------------------------------------------------
// k3 (unchanged, passed R3-R9): radix-select exact 256th-largest key,
// compact >= T, bitonic-sort 512 -> exact jax.lax.top_k order.
// Also writes the full sw plane.
// ---------------------------------------------------------------------------
__global__ __launch_bounds__(512) void k_topk(
        const float* __restrict__ norms, unsigned int* __restrict__ topk,
        float* __restrict__ sw_out) {
    __shared__ unsigned int keys[HW_];               // 12.25 KB
    __shared__ unsigned int hist[256];
    __shared__ unsigned long long sortbuf[512];      // 4 KB
    __shared__ unsigned int s_prefix, s_need, s_cnt;
    __shared__ unsigned char flags[HW_];

    int b = blockIdx.x;
    int t = threadIdx.x;
    const float* nb = norms + b * HW_;

    for (int i = t; i < HW_; i += 512) {
        keys[i] = __float_as_uint(nb[i]);
        flags[i] = 0;
    }
    if (t == 0) { s_prefix = 0u; s_need = K_; s_cnt = 0u; }
    for (int i = t; i < 512; i += 512) sortbuf[i] = ~0ULL;

    for (int r = 0; r < 4; ++r) {
        if (t < 256) hist[t] = 0u;
        __syncthreads();
        unsigned int pfx = s_prefix;
        int shift = 24 - 8 * r;
        for (int i = t; i < HW_; i += 512) {
            unsigned int k = keys[i];
            bool ok = (r == 0) || ((k >> (32 - 8 * r)) == pfx);
            if (ok) atomicAdd(&hist[(k >> shift) & 0xFFu], 1u);
        }
        __syncthreads();
        if (t < 64) {                                // wave 0: suffix-scan
            unsigned int h0 = hist[4 * t + 0];
            unsigned int h1 = hist[4 * t + 1];
            unsigned int h2 = hist[4 * t + 2];
            unsigned int h3 = hist[4 * t + 3];
            unsigned int tot = h0 + h1 + h2 + h3;
            unsigned int suf = tot;
            #pragma unroll
            for (int off = 1; off < 64; off <<= 1) {
                unsigned int v = __shfl_down(suf, off);
                suf += (t + off < 64) ? v : 0u;
            }
            unsigned int g0 = suf;
            unsigned int g1 = suf - h0;
            unsigned int g2 = g1 - h1;
            unsigned int g3 = g2 - h2;
            unsigned int g4 = g3 - h3;
            unsigned int need = s_need;
            if (g0 >= need && g1 < need) { s_prefix = (pfx << 8) | (4u*t+0u); s_need = need - g1; }
            if (g1 >= need && g2 < need) { s_prefix = (pfx << 8) | (4u*t+1u); s_need = need - g2; }
            if (g2 >= need && g3 < need) { s_prefix = (pfx << 8) | (4u*t+2u); s_need = need - g3; }
            if (g3 >= need && g4 < need) { s_prefix = (pfx << 8) | (4u*t+3u); s_need = need - g4; }
        }
        __syncthreads();
    }
    unsigned int T = s_prefix;

    for (int i = t; i < HW_; i += 512) {
        unsigned int k = keys[i];
        if (k >= T) {
            unsigned int pos = atomicAdd(&s_cnt, 1u);
            if (pos < 512)
                sortbuf[pos] = ((unsigned long long)(~k) << 32) | (unsigned int)i;
        }
    }
    __syncthreads();

    for (int kk = 2; kk <= 512; kk <<= 1) {
        for (int j = kk >> 1; j > 0; j >>= 1) {
            int ixj = t ^ j;
            if (ixj > t) {
                unsigned long long a = sortbuf[t], c = sortbuf[ixj];
                bool up = ((t & kk) == 0);
                if ((a > c) == up) { sortbuf[t] = c; sortbuf[ixj] = a; }
            }
            __syncthreads();
        }
    }

    if (t < K_) {
        unsigned long long e = sortbuf[t];
        unsigned int idx = (unsigned int)(e & 0xFFFFFFFFu);
        topk[b * K_ + t] = idx;
        flags[idx] = 1;
    }
    __syncthreads();

    float* swb = sw_out + b * HW_;
    for (int i = t; i < HW_; i += 512)
        swb[i] = flags[i] ? 1.0f : 0.0f;
}

// ---------------------------------------------------------------------------
// k4 (passed R9): gather from [b][pix][o]: lane o reads feats[b][p][o] ->
// one dense 256B read per wave. Writes the 67-float points row.
// ---------------------------------------------------------------------------
__global__ __launch_bounds__(64) void k_points(
        const float* __restrict__ feats, const unsigned int* __restrict__ topk,
        float* __restrict__ points) {
    int bk = blockIdx.x;                             // 0 .. B*K-1
    int b = bk >> 8;                                 // K = 256
    int o = threadIdx.x;
    unsigned int p = topk[bk];

    float v = feats[((size_t)b * HW_ + p) * C_ENC_ + o];
    float* row = points + (size_t)bk * PTS_ROW_;
    row[3 + o] = v;
    if (o == 0) {
        row[0] = (float)(p % W_);                    // abs_ (x)
        row[1] = (float)(p / W_);                    // ord_ (y)
        row[2] = 0.0f;                               // depth
    }
}

// ---------------------------------------------------------------------------
// k5 (passed R9): x_out[b][o] = mean over K of feats[b][idx_k][o],
// k ascending (reference order). Dense 256B read per k.
// ---------------------------------------------------------------------------
__global__ __launch_bounds__(64) void k_xout(
        const float* __restrict__ feats, const unsigned int* __restrict__ topk,
        float* __restrict__ xout) {
    __shared__ unsigned int sidx[K_];
    int b = blockIdx.x;
    int t = threadIdx.x;
    for (int r = t; r < K_; r += 64) sidx[r] = topk[b * K_ + r];
    __syncthreads();

    const float* fb = feats + (size_t)b * HW_ * C_ENC_ + t;
    float s = 0.0f;
    #pragma unroll 8
    for (int k = 0; k < K_; ++k) s += fb[(size_t)sidx[k] * C_ENC_];
    xout[b * C_ENC_ + t] = s * (1.0f / K_);
}

// ---------------------------------------------------------------------------
extern "C" void kernel_launch(void* const* d_in, const int* in_sizes, int n_in,
                              void* d_out, int out_size, void* d_ws, size_t ws_size,
                              hipStream_t stream) {
    const float* F    = (const float*)d_in[0];       // [B, C_IN, H, W]
    const float* w    = (const float*)d_in[1];       // [C_ENC, C_IN]
    const float* bias = (const float*)d_in[2];       // [C_ENC]

    float* out    = (float*)d_out;
    float* xout   = out;                             // [B, C_ENC]      (2048)
    float* sw     = out + B_ * C_ENC_;               // [B, 1, H, W]    (100352)
    float* points = sw + BHW_;                       // [B, K, 67]      (548864)

    // workspace: feats [B,HW,64] 25.7MB | Wt 128KB | norms 392KB | topk 32KB
    float* feats         = (float*)d_ws;
    float* wt            = feats + (size_t)BHW_ * C_ENC_;
    float* norms         = wt + C_IN_ * C_ENC_;
    unsigned int* topk   = (unsigned int*)(norms + BHW_);

    k_transpose_w<<<128, 256, 0, stream>>>(w, wt);
    k_conv       <<<BHW_ / 64, 256, 0, stream>>>(F, wt, bias, feats);
    k_norm       <<<BHW_ / 256, 256, 0, stream>>>(feats, norms);
    k_topk       <<<B_, 512, 0, stream>>>(norms, topk, sw);
    k_points     <<<B_ * K_, 64, 0, stream>>>(feats, topk, points);
    k_xout       <<<B_, 64, 0, stream>>>(feats, topk, xout);
}